// Round 8
// baseline (293.601 us; speedup 1.0000x reference)
//
#include <hip/hip_runtime.h>
#include <hip/hip_bf16.h>
#include <cstdint>
#include <cstddef>

#define BB 32
#define SS 4096
#define DD 256
#define UU 256
#define BM 64
#define NCH (SS / BM)   // 64 chunks per batch

typedef __attribute__((ext_vector_type(8))) short short8;
typedef __attribute__((ext_vector_type(4))) float f32x4;

__device__ __forceinline__ unsigned short f2bf(float x) {
  union { float f; unsigned int u; } c; c.f = x;
  unsigned int r = c.u + 0x7FFFu + ((c.u >> 16) & 1u);
  return (unsigned short)(r >> 16);
}

// pack2(lo, hi) -> u32 [bf16(hi)<<16 | bf16(lo)], round-half-up
__device__ __forceinline__ unsigned int bfpack2(float lo, float hi) {
  union { float f; unsigned int u; } a, b;
  a.f = hi; b.f = lo;
  return __builtin_amdgcn_perm(a.u + 0x8000u, b.u + 0x8000u, 0x07060302u);
}

__device__ __forceinline__ short8 bfpack8(float4 f0, float4 f1) {
  union { unsigned int u[4]; short8 s; } r;
  r.u[0] = bfpack2(f0.x, f0.y);
  r.u[1] = bfpack2(f0.z, f0.w);
  r.u[2] = bfpack2(f1.x, f1.y);
  r.u[3] = bfpack2(f1.z, f1.w);
  return r.s;
}

// K1: posb[b][u] = position[b] @ W1[:,u] + b1[u] + b2[u]   (exact fp32)
__global__ void k_posproj(const float* __restrict__ pos, const float* __restrict__ W1,
                          const float* __restrict__ b1, const float* __restrict__ b2,
                          float* __restrict__ posb) {
  __shared__ float p[DD];
  int b = blockIdx.x, u = threadIdx.x;
  p[u] = pos[b * DD + u];
  __syncthreads();
  float acc = b1[u] + b2[u];
#pragma unroll 4
  for (int d = 0; d < DD; ++d) acc = fmaf(p[d], W1[(size_t)d * UU + u], acc);
  posb[b * UU + u] = acc;
}

// K1b: w2t[u][d] = bf16(W2[d][u])  (tiled transpose)
__global__ void k_w2t(const float* __restrict__ W2, unsigned short* __restrict__ w2t) {
  __shared__ unsigned short tile[16][17];
  int di = blockIdx.x * 16, ui = blockIdx.y * 16;
  int t = threadIdx.x;
  int r = t >> 4, c = t & 15;
  tile[c][r] = f2bf(W2[(size_t)(di + r) * UU + ui + c]);
  __syncthreads();
  w2t[(size_t)(ui + r) * DD + di + c] = tile[r][c];
}

// ============ PRODUCTION KERNEL (unchanged from r7, known 77 us) ============
__global__ __launch_bounds__(512, 4) void k_score_ctx(
    const float* __restrict__ options, const unsigned short* __restrict__ w2t,
    const float* __restrict__ posb, const float* __restrict__ V,
    const float* __restrict__ bvp, float* __restrict__ scores,
    float* __restrict__ part, float2* __restrict__ ml) {
  __shared__ __align__(16) unsigned char smem[81920];   // 80 KB
  unsigned char* const bufB = smem + 32768;

  const int tid = threadIdx.x;
  const int ch = blockIdx.x;            // 0..63
  const int b  = blockIdx.y;
  const int s0 = ch * BM;
  const int wid = tid >> 6, l = tid & 63;
  const int wr = wid >> 2;              // 0..1  (32-row half)
  const int wc = wid & 3;               // 0..3  (64-u quarter)
  const int il = l & 15, kg = l >> 4;

  const float* optb = options + ((size_t)b * SS + s0) * DD;

  // ---- A static stage: 64 rows x 256 k (fp32 -> bf16, swizzled) ----
  {
    const int arow = tid >> 3;          // 0..63
    const int acs  = tid & 7;
    const float* pa = optb + (size_t)arow * DD;
#pragma unroll
    for (int j = 0; j < 4; ++j) {
      int o = j * 8 + acs;              // logical 16B-octet 0..31
      float4 f0 = *(const float4*)(pa + o * 8);
      float4 f1 = *(const float4*)(pa + o * 8 + 4);
      *(short8*)(smem + arow * 512 + ((o ^ (arow & 31)) << 4)) = bfpack8(f0, f1);
    }
  }

  int uB0, uB1;
  const unsigned short *srcB0, *srcB1;
  {
    int p0 = (wid * 2) * 64 + l;
    int p1 = p0 + 64;
    uB0 = p0 >> 2; uB1 = p1 >> 2;
    int s0b = (p0 & 3) ^ ((uB0 >> 1) & 3);
    int s1b = (p1 & 3) ^ ((uB1 >> 1) & 3);
    srcB0 = w2t + (size_t)uB0 * DD + s0b * 8;
    srcB1 = w2t + (size_t)uB1 * DD + s1b * 8;
  }

#define GLLB(T, SLOT)                                                            \
  {                                                                              \
    __builtin_amdgcn_global_load_lds(                                            \
        (const __attribute__((address_space(1))) void*)(srcB0 + (T) * 32),       \
        (__attribute__((address_space(3))) void*)(bufB + (SLOT) * 16384 + (wid * 2) * 1024), \
        16, 0, 0);                                                               \
    __builtin_amdgcn_global_load_lds(                                            \
        (const __attribute__((address_space(1))) void*)(srcB1 + (T) * 32),       \
        (__attribute__((address_space(3))) void*)(bufB + (SLOT) * 16384 + (wid * 2 + 1) * 1024), \
        16, 0, 0);                                                               \
  }

  int abase[2], as_[2];
#pragma unroll
  for (int mi = 0; mi < 2; ++mi) {
    int r = wr * 32 + mi * 16 + il;
    abase[mi] = r * 512;
    as_[mi] = r & 31;
  }
  int boffs[4];
#pragma unroll
  for (int ni = 0; ni < 4; ++ni) {
    int u = wc * 64 + ni * 16 + il;
    boffs[ni] = u * 64 + ((kg ^ ((u >> 1) & 3)) << 4);
  }

  f32x4 acc[2][4];
#pragma unroll
  for (int mi = 0; mi < 2; ++mi)
#pragma unroll
    for (int ni = 0; ni < 4; ++ni) {
      f32x4 z = {0.f, 0.f, 0.f, 0.f};
      acc[mi][ni] = z;
    }

  GLLB(0, 0);
  GLLB(1, 1);
  asm volatile("s_waitcnt vmcnt(2) lgkmcnt(0)" ::: "memory");
  __builtin_amdgcn_sched_barrier(0);
  __builtin_amdgcn_s_barrier();

#pragma unroll
  for (int t = 0; t < 8; ++t) {
    if (t < 6) GLLB(t + 2, (t + 2) % 3);
    const unsigned char* bC = bufB + (t % 3) * 16384;
    short8 af[2];
#pragma unroll
    for (int mi = 0; mi < 2; ++mi)
      af[mi] = *(const short8*)(smem + abase[mi] + (((4 * t + kg) ^ as_[mi]) << 4));
    __builtin_amdgcn_s_setprio(1);
#pragma unroll
    for (int ni = 0; ni < 4; ++ni) {
      short8 bf = *(const short8*)(bC + boffs[ni]);
      acc[0][ni] = __builtin_amdgcn_mfma_f32_16x16x32_bf16(af[0], bf, acc[0][ni], 0, 0, 0);
      acc[1][ni] = __builtin_amdgcn_mfma_f32_16x16x32_bf16(af[1], bf, acc[1][ni], 0, 0, 0);
    }
    __builtin_amdgcn_s_setprio(0);
    if (t < 6) {
      asm volatile("s_waitcnt vmcnt(2)" ::: "memory");
    } else if (t == 6) {
      asm volatile("s_waitcnt vmcnt(0)" ::: "memory");
    }
    if (t < 7) {
      __builtin_amdgcn_sched_barrier(0);
      __builtin_amdgcn_s_barrier();
    }
  }
#undef GLLB

  __syncthreads();

  float (*red)[4] = (float (*)[4])smem;
  float* pbuf     = (float*)(smem + 1024);
  float4* pr      = (float4*)(smem + 2048);

  float part_r[2][4];
#pragma unroll
  for (int mi = 0; mi < 2; ++mi)
#pragma unroll
    for (int r = 0; r < 4; ++r) part_r[mi][r] = 0.f;

#pragma unroll
  for (int ni = 0; ni < 4; ++ni) {
    int u = wc * 64 + ni * 16 + il;
    float pv = posb[b * UU + u];
    float vv = V[u];
#pragma unroll
    for (int mi = 0; mi < 2; ++mi)
#pragma unroll
      for (int r = 0; r < 4; ++r) {
        float x = acc[mi][ni][r] + pv;
        float tnh = 1.f - __fdividef(2.f, __expf(2.f * x) + 1.f);
        part_r[mi][r] = fmaf(tnh, vv, part_r[mi][r]);
      }
  }
#pragma unroll
  for (int mi = 0; mi < 2; ++mi)
#pragma unroll
    for (int r = 0; r < 4; ++r) {
      float p = part_r[mi][r];
      p += __shfl_xor(p, 1);
      p += __shfl_xor(p, 2);
      p += __shfl_xor(p, 4);
      p += __shfl_xor(p, 8);
      part_r[mi][r] = p;
    }
  if (il == 0) {
#pragma unroll
    for (int mi = 0; mi < 2; ++mi)
#pragma unroll
      for (int r = 0; r < 4; ++r)
        red[wr * 32 + mi * 16 + kg * 4 + r][wc] = part_r[mi][r];
  }
  __syncthreads();

  const float bvv = bvp[0];
  if (tid < 64) {
    float4 r0 = *(const float4*)red[tid];
    float sv = r0.x + r0.y + r0.z + r0.w + bvv;
    scores[(size_t)b * SS + s0 + tid] = sv;
    float m = sv;
#pragma unroll
    for (int off = 32; off >= 1; off >>= 1) m = fmaxf(m, __shfl_xor(m, off));
    float p = __expf(sv - m);
    float ls = p;
#pragma unroll
    for (int off = 32; off >= 1; off >>= 1) ls += __shfl_xor(ls, off);
    pbuf[tid] = p;
    if (tid == 0) ml[b * NCH + ch] = make_float2(m, ls);
  }
  __syncthreads();

  {
    int rg = tid >> 6;
    int d4 = (tid & 63) << 2;
    float a0 = 0.f, a1 = 0.f, a2 = 0.f, a3 = 0.f;
#pragma unroll
    for (int i = 0; i < 8; ++i) {
      int s = i * 8 + rg;
      const float4 o = *(const float4*)(optb + (size_t)s * DD + d4);
      float w = pbuf[s];
      a0 = fmaf(w, o.x, a0); a1 = fmaf(w, o.y, a1);
      a2 = fmaf(w, o.z, a2); a3 = fmaf(w, o.w, a3);
    }
    pr[tid] = make_float4(a0, a1, a2, a3);
  }
  __syncthreads();
  if (tid < 64) {
    float4 o = pr[tid];
#pragma unroll
    for (int g = 1; g < 8; ++g) {
      float4 v = pr[g * 64 + tid];
      o.x += v.x; o.y += v.y; o.z += v.z; o.w += v.w;
    }
    *(float4*)&part[(((size_t)b * NCH + ch) * DD) + (tid << 2)] = o;
  }
}

// ============ DIAGNOSTIC ABLATION KERNEL (writes to scratch only) ============
// PHASES: 1 = A-stage only; 2 = +K-loop(MFMA); 3 = +tanh/softmax epilogue.
// REP: amplification; rep r reads batch (blockIdx.y + 8r) & 31 (HBM/L3-cold-ish).
#define GLLB2(T, SLOT)                                                           \
  {                                                                              \
    __builtin_amdgcn_global_load_lds(                                            \
        (const __attribute__((address_space(1))) void*)(srcB0 + (T) * 32),       \
        (__attribute__((address_space(3))) void*)(bufB + (SLOT) * 16384 + (wid * 2) * 1024), \
        16, 0, 0);                                                               \
    __builtin_amdgcn_global_load_lds(                                            \
        (const __attribute__((address_space(1))) void*)(srcB1 + (T) * 32),       \
        (__attribute__((address_space(3))) void*)(bufB + (SLOT) * 16384 + (wid * 2 + 1) * 1024), \
        16, 0, 0);                                                               \
  }

template<int PHASES, int REP>
__global__ __launch_bounds__(512, 4) void k_diag(
    const float* __restrict__ options, const unsigned short* __restrict__ w2t,
    const float* __restrict__ posb, const float* __restrict__ V,
    const float* __restrict__ bvp, float* __restrict__ dbg) {
  __shared__ __align__(16) unsigned char smem[81920];
  unsigned char* const bufB = smem + 32768;

  const int tid = threadIdx.x;
  const int ch = blockIdx.x;
  const int s0 = ch * BM;
  const int wid = tid >> 6, l = tid & 63;
  const int wr = wid >> 2, wc = wid & 3;
  const int il = l & 15, kg = l >> 4;

  float*  dbg_scores = dbg;                                 // [32][4096] by blockIdx.y
  float2* dbg_ml     = (float2*)(dbg + BB * SS);            // [32][64]
  float*  dbg_sink   = dbg + BB * SS + 2 * BB * NCH;

  const int arow = tid >> 3, acs = tid & 7;
  int uB0, uB1;
  const unsigned short *srcB0, *srcB1;
  {
    int p0 = (wid * 2) * 64 + l;
    int p1 = p0 + 64;
    uB0 = p0 >> 2; uB1 = p1 >> 2;
    int s0b = (p0 & 3) ^ ((uB0 >> 1) & 3);
    int s1b = (p1 & 3) ^ ((uB1 >> 1) & 3);
    srcB0 = w2t + (size_t)uB0 * DD + s0b * 8;
    srcB1 = w2t + (size_t)uB1 * DD + s1b * 8;
  }
  int abase[2], as_[2];
#pragma unroll
  for (int mi = 0; mi < 2; ++mi) {
    int r = wr * 32 + mi * 16 + il;
    abase[mi] = r * 512;
    as_[mi] = r & 31;
  }
  int boffs[4];
#pragma unroll
  for (int ni = 0; ni < 4; ++ni) {
    int u = wc * 64 + ni * 16 + il;
    boffs[ni] = u * 64 + ((kg ^ ((u >> 1) & 3)) << 4);
  }

  f32x4 acc[2][4];
#pragma unroll
  for (int mi = 0; mi < 2; ++mi)
#pragma unroll
    for (int ni = 0; ni < 4; ++ni) {
      f32x4 z = {0.f, 0.f, 0.f, 0.f};
      acc[mi][ni] = z;
    }
  float sink = 0.f;

  for (int rep = 0; rep < REP; ++rep) {
    const int bb = (blockIdx.y + rep * 8) & 31;
    const float* optb = options + ((size_t)bb * SS + s0) * DD;

    // ---- A-stage (always) ----
    {
      const float* pa = optb + (size_t)arow * DD;
#pragma unroll
      for (int j = 0; j < 4; ++j) {
        int o = j * 8 + acs;
        float4 f0 = *(const float4*)(pa + o * 8);
        float4 f1 = *(const float4*)(pa + o * 8 + 4);
        *(short8*)(smem + arow * 512 + ((o ^ (arow & 31)) << 4)) = bfpack8(f0, f1);
      }
    }
    if (PHASES == 1) {
      __syncthreads();
      sink += *(volatile float*)(smem + ((tid * 16) & 32767));
      __syncthreads();
      continue;
    }

    // ---- prologue + K-loop ----
    GLLB2(0, 0);
    GLLB2(1, 1);
    asm volatile("s_waitcnt vmcnt(2) lgkmcnt(0)" ::: "memory");
    __builtin_amdgcn_sched_barrier(0);
    __builtin_amdgcn_s_barrier();

#pragma unroll
    for (int t = 0; t < 8; ++t) {
      if (t < 6) GLLB2(t + 2, (t + 2) % 3);
      const unsigned char* bC = bufB + (t % 3) * 16384;
      short8 af[2];
#pragma unroll
      for (int mi = 0; mi < 2; ++mi)
        af[mi] = *(const short8*)(smem + abase[mi] + (((4 * t + kg) ^ as_[mi]) << 4));
      __builtin_amdgcn_s_setprio(1);
#pragma unroll
      for (int ni = 0; ni < 4; ++ni) {
        short8 bf = *(const short8*)(bC + boffs[ni]);
        acc[0][ni] = __builtin_amdgcn_mfma_f32_16x16x32_bf16(af[0], bf, acc[0][ni], 0, 0, 0);
        acc[1][ni] = __builtin_amdgcn_mfma_f32_16x16x32_bf16(af[1], bf, acc[1][ni], 0, 0, 0);
      }
      __builtin_amdgcn_s_setprio(0);
      if (t < 6) {
        asm volatile("s_waitcnt vmcnt(2)" ::: "memory");
      } else if (t == 6) {
        asm volatile("s_waitcnt vmcnt(0)" ::: "memory");
      }
      if (t < 7) {
        __builtin_amdgcn_sched_barrier(0);
        __builtin_amdgcn_s_barrier();
      }
    }
    __syncthreads();

    if (PHASES >= 3) {
      float (*red)[4] = (float (*)[4])smem;
      float* pbuf     = (float*)(smem + 1024);

      float part_r[2][4];
#pragma unroll
      for (int mi = 0; mi < 2; ++mi)
#pragma unroll
        for (int r = 0; r < 4; ++r) part_r[mi][r] = 0.f;

#pragma unroll
      for (int ni = 0; ni < 4; ++ni) {
        int u = wc * 64 + ni * 16 + il;
        float pv = posb[bb * UU + u];
        float vv = V[u];
#pragma unroll
        for (int mi = 0; mi < 2; ++mi)
#pragma unroll
          for (int r = 0; r < 4; ++r) {
            float x = acc[mi][ni][r] + pv;
            float tnh = 1.f - __fdividef(2.f, __expf(2.f * x) + 1.f);
            part_r[mi][r] = fmaf(tnh, vv, part_r[mi][r]);
          }
      }
#pragma unroll
      for (int mi = 0; mi < 2; ++mi)
#pragma unroll
        for (int r = 0; r < 4; ++r) {
          float p = part_r[mi][r];
          p += __shfl_xor(p, 1);
          p += __shfl_xor(p, 2);
          p += __shfl_xor(p, 4);
          p += __shfl_xor(p, 8);
          part_r[mi][r] = p;
        }
      if (il == 0) {
#pragma unroll
        for (int mi = 0; mi < 2; ++mi)
#pragma unroll
          for (int r = 0; r < 4; ++r)
            red[wr * 32 + mi * 16 + kg * 4 + r][wc] = part_r[mi][r];
      }
      __syncthreads();

      const float bvv = bvp[0];
      if (tid < 64) {
        float4 r0 = *(const float4*)red[tid];
        float sv = r0.x + r0.y + r0.z + r0.w + bvv;
        dbg_scores[(size_t)blockIdx.y * SS + s0 + tid] = sv;
        float m = sv;
#pragma unroll
        for (int off = 32; off >= 1; off >>= 1) m = fmaxf(m, __shfl_xor(m, off));
        float p = __expf(sv - m);
        float ls = p;
#pragma unroll
        for (int off = 32; off >= 1; off >>= 1) ls += __shfl_xor(ls, off);
        pbuf[tid] = p;
        if (tid == 0) dbg_ml[blockIdx.y * NCH + ch] = make_float2(m, ls);
      }
      __syncthreads();
      sink += pbuf[tid & 63];
      __syncthreads();
    }
  }

  sink += acc[0][0][0] + acc[1][3][3];
  if (tid == 0) dbg_sink[blockIdx.y * NCH + ch] = sink;
}
#undef GLLB2

// K3: per batch — combine 64 chunk partials, emit context + weights
__global__ __launch_bounds__(256) void k_final(
    const float* __restrict__ scores, const float* __restrict__ part,
    const float2* __restrict__ ml, float* __restrict__ ctx,
    float* __restrict__ wgt) {
  __shared__ float ms[NCH], lsh[NCH];
  int b = blockIdx.x, t = threadIdx.x;
  if (t < NCH) { float2 v = ml[b * NCH + t]; ms[t] = v.x; lsh[t] = v.y; }
  __syncthreads();
  float gm = ms[0];
#pragma unroll
  for (int i = 1; i < NCH; ++i) gm = fmaxf(gm, ms[i]);
  float gs = 0.f;
#pragma unroll
  for (int i = 0; i < NCH; ++i) gs += lsh[i] * __expf(ms[i] - gm);
  float inv = 1.f / gs;
  float acc = 0.f;
#pragma unroll 4
  for (int i = 0; i < NCH; ++i)
    acc += part[((size_t)b * NCH + i) * DD + t] * __expf(ms[i] - gm);
  ctx[b * DD + t] = acc * inv;
  const float* sb = scores + (size_t)b * SS;
  float* wb = wgt + (size_t)b * SS;
#pragma unroll 4
  for (int i = 0; i < 16; ++i) {
    int s = i * 256 + t;
    wb[s] = __expf(sb[s] - gm) * inv;
  }
}

extern "C" void kernel_launch(void* const* d_in, const int* in_sizes, int n_in,
                              void* d_out, int out_size, void* d_ws, size_t ws_size,
                              hipStream_t stream) {
  const float* position = (const float*)d_in[0];
  const float* options  = (const float*)d_in[1];
  const float* W1 = (const float*)d_in[2];
  const float* b1 = (const float*)d_in[3];
  const float* W2 = (const float*)d_in[4];
  const float* b2 = (const float*)d_in[5];
  const float* V  = (const float*)d_in[6];
  const float* bv = (const float*)d_in[7];

  float* out = (float*)d_out;
  float* ctx_out = out;              // [32,256]
  float* wgt_out = out + BB * DD;    // [32,4096]

  char* ws = (char*)d_ws;
  float* posb         = (float*)ws;                          // 32 KB
  unsigned short* w2t = (unsigned short*)(ws + 32 * 1024);   // 128 KB
  float* scores       = (float*)(ws + 160 * 1024);           // 512 KB
  float* part         = (float*)(ws + 672 * 1024);           // 2 MB
  float2* ml          = (float2*)(ws + 672 * 1024 + 2 * 1024 * 1024); // 16 KB
  float* dbg0         = (float*)(ws + (size_t)8  * 1024 * 1024);
  float* dbg1         = (float*)(ws + (size_t)16 * 1024 * 1024);
  float* dbg2         = (float*)(ws + (size_t)24 * 1024 * 1024);

  k_posproj<<<BB, 256, 0, stream>>>(position, W1, b1, b2, posb);
  k_w2t<<<dim3(16, 16), 256, 0, stream>>>(W2, w2t);
  k_score_ctx<<<dim3(NCH, BB), 512, 0, stream>>>(options, w2t, posb, V, bv,
                                                 scores, part, ml);
  k_final<<<BB, 256, 0, stream>>>(scores, part, ml, ctx_out, wgt_out);

  // ---- diagnostic ablations (scratch-only, deterministic) ----
  k_diag<3, 2><<<dim3(NCH, BB), 512, 0, stream>>>(options, w2t, posb, V, bv, dbg0);
  k_diag<2, 2><<<dim3(NCH, BB), 512, 0, stream>>>(options, w2t, posb, V, bv, dbg1);
  k_diag<1, 3><<<dim3(NCH, BB), 512, 0, stream>>>(options, w2t, posb, V, bv, dbg2);
}

// Round 9
// 112.768 us; speedup vs baseline: 2.6036x; 2.6036x over previous
//
#include <hip/hip_runtime.h>
#include <hip/hip_bf16.h>
#include <cstdint>
#include <cstddef>

#define BB 32
#define SS 4096
#define DD 256
#define UU 256
#define BM 64
#define NCH (SS / BM)   // 64 chunks per batch
#define CPB 4           // chunks per block

typedef __attribute__((ext_vector_type(8))) short short8;
typedef __attribute__((ext_vector_type(4))) float f32x4;

__device__ __forceinline__ unsigned short f2bf(float x) {
  union { float f; unsigned int u; } c; c.f = x;
  unsigned int r = c.u + 0x7FFFu + ((c.u >> 16) & 1u);
  return (unsigned short)(r >> 16);
}

// pack2(lo, hi) -> u32 [bf16(hi)<<16 | bf16(lo)], round-half-up
__device__ __forceinline__ unsigned int bfpack2(float lo, float hi) {
  union { float f; unsigned int u; } a, b;
  a.f = hi; b.f = lo;
  return __builtin_amdgcn_perm(a.u + 0x8000u, b.u + 0x8000u, 0x07060302u);
}

__device__ __forceinline__ short8 bfpack8(float4 f0, float4 f1) {
  union { unsigned int u[4]; short8 s; } r;
  r.u[0] = bfpack2(f0.x, f0.y);
  r.u[1] = bfpack2(f0.z, f0.w);
  r.u[2] = bfpack2(f1.x, f1.y);
  r.u[3] = bfpack2(f1.z, f1.w);
  return r.s;
}

// K1: posb[b][u] = position[b] @ W1[:,u] + b1[u] + b2[u]   (exact fp32)
__global__ void k_posproj(const float* __restrict__ pos, const float* __restrict__ W1,
                          const float* __restrict__ b1, const float* __restrict__ b2,
                          float* __restrict__ posb) {
  __shared__ float p[DD];
  int b = blockIdx.x, u = threadIdx.x;
  p[u] = pos[b * DD + u];
  __syncthreads();
  float acc = b1[u] + b2[u];
#pragma unroll 4
  for (int d = 0; d < DD; ++d) acc = fmaf(p[d], W1[(size_t)d * UU + u], acc);
  posb[b * UU + u] = acc;
}

// K1b: w2t[u][d] = bf16(W2[d][u])  (tiled transpose)
__global__ void k_w2t(const float* __restrict__ W2, unsigned short* __restrict__ w2t) {
  __shared__ unsigned short tile[16][17];
  int di = blockIdx.x * 16, ui = blockIdx.y * 16;
  int t = threadIdx.x;
  int r = t >> 4, c = t & 15;
  tile[c][r] = f2bf(W2[(size_t)(di + r) * UU + ui + c]);
  __syncthreads();
  w2t[(size_t)(ui + r) * DD + di + c] = tile[r][c];
}

// K2 (fused, cross-chunk pipelined): each block processes CPB=4 chunks of 64 rows.
// B tiles flow continuously (tile g -> slot g%3, src (g&7)*32, L2-hot re-reads).
// A[cc+1] global loads issue right after chunk cc's K-loop, pack after ctx.
// ctx computed from bf16 A tile in LDS (no fp32 re-read).
// LDS: A [64 rows][32 octets 16B, phys o^(row&31)] = 32 KB @ 0
//      B 3 x 16 KB slots @ 32768; epilogue scratch in the free slot (8cc+7)%3.
__global__ __launch_bounds__(512, 4) void k_score_ctx(
    const float* __restrict__ options, const unsigned short* __restrict__ w2t,
    const float* __restrict__ posb, const float* __restrict__ V,
    const float* __restrict__ bvp, float* __restrict__ scores,
    float* __restrict__ part, float2* __restrict__ ml) {
  __shared__ __align__(16) unsigned char smem[81920];   // 80 KB
  unsigned char* const bufB = smem + 32768;

  const int tid = threadIdx.x;
  const int chBase = blockIdx.x * CPB;
  const int b  = blockIdx.y;
  const int wid = tid >> 6, l = tid & 63;
  const int wr = wid >> 2;              // 0..1  (32-row half)
  const int wc = wid & 3;               // 0..3  (64-u quarter)
  const int il = l & 15, kg = l >> 4;

  // ---- B gll lane geometry (physical slot -> inverse-swizzled source) ----
  const unsigned short *srcB0, *srcB1;
  {
    int p0 = (wid * 2) * 64 + l;
    int p1 = p0 + 64;
    int u0 = p0 >> 2, u1 = p1 >> 2;
    int s0b = (p0 & 3) ^ ((u0 >> 1) & 3);
    int s1b = (p1 & 3) ^ ((u1 >> 1) & 3);
    srcB0 = w2t + (size_t)u0 * DD + s0b * 8;
    srcB1 = w2t + (size_t)u1 * DD + s1b * 8;
  }

#define GLLB(OFF, SLOT)                                                          \
  {                                                                              \
    __builtin_amdgcn_global_load_lds(                                            \
        (const __attribute__((address_space(1))) void*)(srcB0 + (OFF)),          \
        (__attribute__((address_space(3))) void*)(bufB + (SLOT) * 16384 + (wid * 2) * 1024), \
        16, 0, 0);                                                               \
    __builtin_amdgcn_global_load_lds(                                            \
        (const __attribute__((address_space(1))) void*)(srcB1 + (OFF)),          \
        (__attribute__((address_space(3))) void*)(bufB + (SLOT) * 16384 + (wid * 2 + 1) * 1024), \
        16, 0, 0);                                                               \
  }

  // ---- A staging geometry ----
  const int arow = tid >> 3;            // 0..63
  const int acs  = tid & 7;
  int awrb[4];
#pragma unroll
  for (int j = 0; j < 4; ++j)
    awrb[j] = arow * 512 + (((j * 8 + acs) ^ (arow & 31)) << 4);

  // ---- MFMA read offsets ----
  int abase[2], as_[2];
#pragma unroll
  for (int mi = 0; mi < 2; ++mi) {
    int r = wr * 32 + mi * 16 + il;
    abase[mi] = r * 512;
    as_[mi] = r & 31;
  }
  int boffs[4];
#pragma unroll
  for (int ni = 0; ni < 4; ++ni) {
    int u = wc * 64 + ni * 16 + il;
    boffs[ni] = u * 64 + ((kg ^ ((u >> 1) & 3)) << 4);
  }

  // ---- hoisted per-lane posb/V fragments ----
  float pvf[4], vvf[4];
#pragma unroll
  for (int ni = 0; ni < 4; ++ni) {
    int u = wc * 64 + ni * 16 + il;
    pvf[ni] = posb[b * UU + u];
    vvf[ni] = V[u];
  }
  const float bvv = bvp[0];

  // ---- prologue: A chunk 0 stage + B tiles 0,1 ----
  {
    const float* pa = options + ((size_t)b * SS + chBase * BM + arow) * DD;
#pragma unroll
    for (int j = 0; j < 4; ++j) {
      float4 f0 = *(const float4*)(pa + (j * 8 + acs) * 8);
      float4 f1 = *(const float4*)(pa + (j * 8 + acs) * 8 + 4);
      *(short8*)(smem + awrb[j]) = bfpack8(f0, f1);
    }
  }
  GLLB(0, 0);
  GLLB(32, 1);
  asm volatile("s_waitcnt vmcnt(2) lgkmcnt(0)" ::: "memory");
  __builtin_amdgcn_sched_barrier(0);
  __builtin_amdgcn_s_barrier();

#pragma unroll
  for (int cc = 0; cc < CPB; ++cc) {
    const int chg = chBase + cc;
    const int s0 = chg * BM;
    const float* optb = options + ((size_t)b * SS + s0) * DD;

    f32x4 acc[2][4];
#pragma unroll
    for (int mi = 0; mi < 2; ++mi)
#pragma unroll
      for (int ni = 0; ni < 4; ++ni) {
        f32x4 z = {0.f, 0.f, 0.f, 0.f};
        acc[mi][ni] = z;
      }

    // ---- K-loop: 8 steps of BK=32, continuous B slot schedule ----
#pragma unroll
    for (int t = 0; t < 8; ++t) {
      const int g = cc * 8 + t;
      if (g + 2 < 8 * CPB) GLLB(((t + 2) & 7) * 32, (g + 2) % 3);
      const unsigned char* bC = bufB + (g % 3) * 16384;
      short8 af[2];
#pragma unroll
      for (int mi = 0; mi < 2; ++mi)
        af[mi] = *(const short8*)(smem + abase[mi] + (((4 * t + kg) ^ as_[mi]) << 4));
      __builtin_amdgcn_s_setprio(1);
#pragma unroll
      for (int ni = 0; ni < 4; ++ni) {
        short8 bf = *(const short8*)(bC + boffs[ni]);
        acc[0][ni] = __builtin_amdgcn_mfma_f32_16x16x32_bf16(af[0], bf, acc[0][ni], 0, 0, 0);
        acc[1][ni] = __builtin_amdgcn_mfma_f32_16x16x32_bf16(af[1], bf, acc[1][ni], 0, 0, 0);
      }
      __builtin_amdgcn_s_setprio(0);
      if (t < 6) {
        asm volatile("s_waitcnt vmcnt(2)" ::: "memory");
      } else if (t == 6) {
        if (cc == CPB - 1) {
          asm volatile("s_waitcnt vmcnt(0)" ::: "memory");
        } else {
          asm volatile("s_waitcnt vmcnt(2)" ::: "memory");
        }
      }
      if (t < 7) {
        __builtin_amdgcn_sched_barrier(0);
        __builtin_amdgcn_s_barrier();
      }
    }
    __syncthreads();   // K-loop done; epi slot free, A tile stable

    // ---- A[cc+1] prefetch: issue global loads now, pack after ctx ----
    float4 aR[8];
    if (cc + 1 < CPB) {
      const float* pn = optb + (size_t)BM * DD + (size_t)arow * DD;
#pragma unroll
      for (int j = 0; j < 4; ++j) {
        aR[2 * j]     = *(const float4*)(pn + (j * 8 + acs) * 8);
        aR[2 * j + 1] = *(const float4*)(pn + (j * 8 + acs) * 8 + 4);
      }
    }

    // ---- epilogue scratch in the free B slot ----
    unsigned char* const eb = bufB + ((8 * cc + 7) % 3) * 16384;
    float (*red)[4] = (float (*)[4])eb;          // [64][4]  (1 KB)
    float* pbuf     = (float*)(eb + 1024);       // [64]
    float* pr       = (float*)(eb + 2048);       // [512]    (2 KB)

    // ---- tanh(acc + posb) * V, reduce over u ----
    float part_r[2][4];
#pragma unroll
    for (int mi = 0; mi < 2; ++mi)
#pragma unroll
      for (int r = 0; r < 4; ++r) part_r[mi][r] = 0.f;

#pragma unroll
    for (int ni = 0; ni < 4; ++ni) {
      float pv = pvf[ni], vv = vvf[ni];
#pragma unroll
      for (int mi = 0; mi < 2; ++mi)
#pragma unroll
        for (int r = 0; r < 4; ++r) {
          float x = acc[mi][ni][r] + pv;
          float tnh = 1.f - __fdividef(2.f, __expf(2.f * x) + 1.f);
          part_r[mi][r] = fmaf(tnh, vv, part_r[mi][r]);
        }
    }
#pragma unroll
    for (int mi = 0; mi < 2; ++mi)
#pragma unroll
      for (int r = 0; r < 4; ++r) {
        float p = part_r[mi][r];
        p += __shfl_xor(p, 1);
        p += __shfl_xor(p, 2);
        p += __shfl_xor(p, 4);
        p += __shfl_xor(p, 8);
        part_r[mi][r] = p;
      }
    if (il == 0) {
#pragma unroll
      for (int mi = 0; mi < 2; ++mi)
#pragma unroll
        for (int r = 0; r < 4; ++r)
          red[wr * 32 + mi * 16 + kg * 4 + r][wc] = part_r[mi][r];
    }
    __syncthreads();

    // ---- softmax stats over 64 rows (wave 0) ----
    if (tid < 64) {
      float4 r0 = *(const float4*)red[tid];
      float sv = r0.x + r0.y + r0.z + r0.w + bvv;
      scores[(size_t)b * SS + s0 + tid] = sv;
      float m = sv;
#pragma unroll
      for (int off = 32; off >= 1; off >>= 1) m = fmaxf(m, __shfl_xor(m, off));
      float p = __expf(sv - m);
      float ls = p;
#pragma unroll
      for (int off = 32; off >= 1; off >>= 1) ls += __shfl_xor(ls, off);
      pbuf[tid] = p;
      if (tid == 0) ml[b * NCH + chg] = make_float2(m, ls);
    }
    __syncthreads();

    // ---- partial context from bf16 A tile in LDS ----
    {
      const int d = tid & 255;
      const int sg = tid >> 8;           // 0..1 -> s-half
      const int oct = d >> 3;
      const int hw = (d & 7) * 2;
      float a0 = 0.f;
#pragma unroll
      for (int i = 0; i < 32; ++i) {
        int s = sg * 32 + i;
        unsigned int bits =
            *(const unsigned short*)(smem + s * 512 + (((oct) ^ (s & 31)) << 4) + hw);
        union { unsigned int u; float f; } cv; cv.u = bits << 16;
        a0 = fmaf(pbuf[s], cv.f, a0);
      }
      pr[tid] = a0;
    }
    __syncthreads();
    if (tid < 256)
      part[((size_t)b * NCH + chg) * DD + tid] = pr[tid] + pr[tid + 256];

    // ---- pack A[cc+1] (compiler inserts the vmcnt wait for aR) ----
    if (cc + 1 < CPB) {
#pragma unroll
      for (int j = 0; j < 4; ++j)
        *(short8*)(smem + awrb[j]) = bfpack8(aR[2 * j], aR[2 * j + 1]);
    }
    __syncthreads();
  }
#undef GLLB
}

// K3: per batch — combine 64 chunk partials, emit context + weights
__global__ __launch_bounds__(256) void k_final(
    const float* __restrict__ scores, const float* __restrict__ part,
    const float2* __restrict__ ml, float* __restrict__ ctx,
    float* __restrict__ wgt) {
  __shared__ float ms[NCH], lsh[NCH];
  int b = blockIdx.x, t = threadIdx.x;
  if (t < NCH) { float2 v = ml[b * NCH + t]; ms[t] = v.x; lsh[t] = v.y; }
  __syncthreads();
  float gm = ms[0];
#pragma unroll
  for (int i = 1; i < NCH; ++i) gm = fmaxf(gm, ms[i]);
  float gs = 0.f;
#pragma unroll
  for (int i = 0; i < NCH; ++i) gs += lsh[i] * __expf(ms[i] - gm);
  float inv = 1.f / gs;
  float acc = 0.f;
#pragma unroll 4
  for (int i = 0; i < NCH; ++i)
    acc += part[((size_t)b * NCH + i) * DD + t] * __expf(ms[i] - gm);
  ctx[b * DD + t] = acc * inv;
  const float* sb = scores + (size_t)b * SS;
  float* wb = wgt + (size_t)b * SS;
#pragma unroll 4
  for (int i = 0; i < 16; ++i) {
    int s = i * 256 + t;
    wb[s] = __expf(sb[s] - gm) * inv;
  }
}

extern "C" void kernel_launch(void* const* d_in, const int* in_sizes, int n_in,
                              void* d_out, int out_size, void* d_ws, size_t ws_size,
                              hipStream_t stream) {
  const float* position = (const float*)d_in[0];
  const float* options  = (const float*)d_in[1];
  const float* W1 = (const float*)d_in[2];
  const float* b1 = (const float*)d_in[3];
  const float* W2 = (const float*)d_in[4];
  const float* b2 = (const float*)d_in[5];
  const float* V  = (const float*)d_in[6];
  const float* bv = (const float*)d_in[7];

  float* out = (float*)d_out;
  float* ctx_out = out;              // [32,256]
  float* wgt_out = out + BB * DD;    // [32,4096]

  char* ws = (char*)d_ws;
  float* posb         = (float*)ws;                          // 32 KB
  unsigned short* w2t = (unsigned short*)(ws + 32 * 1024);   // 128 KB
  float* scores       = (float*)(ws + 160 * 1024);           // 512 KB
  float* part         = (float*)(ws + 672 * 1024);           // 2 MB
  float2* ml          = (float2*)(ws + 672 * 1024 + 2 * 1024 * 1024); // 16 KB

  k_posproj<<<BB, 256, 0, stream>>>(position, W1, b1, b2, posb);
  k_w2t<<<dim3(16, 16), 256, 0, stream>>>(W2, w2t);
  k_score_ctx<<<dim3(NCH / CPB, BB), 512, 0, stream>>>(options, w2t, posb, V, bv,
                                                       scores, part, ml);
  k_final<<<BB, 256, 0, stream>>>(scores, part, ml, ctx_out, wgt_out);
}

// Round 10
// 84.279 us; speedup vs baseline: 3.4837x; 1.3380x over previous
//
#include <hip/hip_runtime.h>
#include <hip/hip_bf16.h>
#include <cstdint>
#include <cstddef>

#define BB 32
#define SS 4096
#define DD 256
#define UU 256
#define BM 64
#define NCH (SS / BM)   // 64 chunks per batch

typedef __attribute__((ext_vector_type(8))) short short8;
typedef __attribute__((ext_vector_type(4))) float f32x4;

__device__ __forceinline__ unsigned short f2bf(float x) {
  union { float f; unsigned int u; } c; c.f = x;
  unsigned int r = c.u + 0x7FFFu + ((c.u >> 16) & 1u);
  return (unsigned short)(r >> 16);
}

// pack2(lo, hi) -> u32 [bf16(hi)<<16 | bf16(lo)], round-half-up
__device__ __forceinline__ unsigned int bfpack2(float lo, float hi) {
  union { float f; unsigned int u; } a, b;
  a.f = hi; b.f = lo;
  return __builtin_amdgcn_perm(a.u + 0x8000u, b.u + 0x8000u, 0x07060302u);
}

__device__ __forceinline__ short8 bfpack8(float4 f0, float4 f1) {
  union { unsigned int u[4]; short8 s; } r;
  r.u[0] = bfpack2(f0.x, f0.y);
  r.u[1] = bfpack2(f0.z, f0.w);
  r.u[2] = bfpack2(f1.x, f1.y);
  r.u[3] = bfpack2(f1.z, f1.w);
  return r.s;
}

// DPP row-rotate add: reduce within a 16-lane row at VALU rate (no DS ops)
template <int CTRL>
__device__ __forceinline__ float dppadd(float x) {
  union { float f; int i; } a, b;
  a.f = x;
  b.i = __builtin_amdgcn_update_dpp(0, a.i, CTRL, 0xF, 0xF, true);
  return x + b.f;
}
__device__ __forceinline__ float row16_sum(float x) {
  x = dppadd<0x128>(x);   // row_ror:8
  x = dppadd<0x124>(x);   // row_ror:4
  x = dppadd<0x122>(x);   // row_ror:2
  x = dppadd<0x121>(x);   // row_ror:1
  return x;
}

// K1: posb[b][u] = position[b] @ W1[:,u] + b1[u] + b2[u]   (exact fp32)
__global__ void k_posproj(const float* __restrict__ pos, const float* __restrict__ W1,
                          const float* __restrict__ b1, const float* __restrict__ b2,
                          float* __restrict__ posb) {
  __shared__ float p[DD];
  int b = blockIdx.x, u = threadIdx.x;
  p[u] = pos[b * DD + u];
  __syncthreads();
  float acc = b1[u] + b2[u];
#pragma unroll 4
  for (int d = 0; d < DD; ++d) acc = fmaf(p[d], W1[(size_t)d * UU + u], acc);
  posb[b * UU + u] = acc;
}

// K1b: w2t[u][d] = bf16(W2[d][u])  (tiled transpose)
__global__ void k_w2t(const float* __restrict__ W2, unsigned short* __restrict__ w2t) {
  __shared__ unsigned short tile[16][17];
  int di = blockIdx.x * 16, ui = blockIdx.y * 16;
  int t = threadIdx.x;
  int r = t >> 4, c = t & 15;
  tile[c][r] = f2bf(W2[(size_t)(di + r) * UU + ui + c]);
  __syncthreads();
  w2t[(size_t)(ui + r) * DD + di + c] = tile[r][c];
}

// K2 (fused, epilogue-lite): A staged once, B triple-buffered gll counted-vmcnt.
// Epilogue: tanh+V, DPP row-reduce (no DS shfl), fixed-reference softmax
// (pbuf = exp(score), no per-chunk max/l), ctx partial from fp32 global.
__global__ __launch_bounds__(512, 4) void k_score_ctx(
    const float* __restrict__ options, const unsigned short* __restrict__ w2t,
    const float* __restrict__ posb, const float* __restrict__ V,
    const float* __restrict__ bvp, float* __restrict__ scores,
    float* __restrict__ part) {
  __shared__ __align__(16) unsigned char smem[81920];   // 80 KB
  unsigned char* const bufB = smem + 32768;

  const int tid = threadIdx.x;
  const int ch = blockIdx.x;            // 0..63
  const int b  = blockIdx.y;
  const int s0 = ch * BM;
  const int wid = tid >> 6, l = tid & 63;
  const int wr = wid >> 2;              // 0..1  (32-row half)
  const int wc = wid & 3;               // 0..3  (64-u quarter)
  const int il = l & 15, kg = l >> 4;

  const float* optb = options + ((size_t)b * SS + s0) * DD;

  // ---- A static stage: 64 rows x 256 k (fp32 -> bf16, swizzled) ----
  {
    const int arow = tid >> 3;          // 0..63
    const int acs  = tid & 7;
    const float* pa = optb + (size_t)arow * DD;
#pragma unroll
    for (int j = 0; j < 4; ++j) {
      int o = j * 8 + acs;              // logical 16B-octet 0..31
      float4 f0 = *(const float4*)(pa + o * 8);
      float4 f1 = *(const float4*)(pa + o * 8 + 4);
      *(short8*)(smem + arow * 512 + ((o ^ (arow & 31)) << 4)) = bfpack8(f0, f1);
    }
  }

  int uB0, uB1;
  const unsigned short *srcB0, *srcB1;
  {
    int p0 = (wid * 2) * 64 + l;
    int p1 = p0 + 64;
    uB0 = p0 >> 2; uB1 = p1 >> 2;
    int s0b = (p0 & 3) ^ ((uB0 >> 1) & 3);
    int s1b = (p1 & 3) ^ ((uB1 >> 1) & 3);
    srcB0 = w2t + (size_t)uB0 * DD + s0b * 8;
    srcB1 = w2t + (size_t)uB1 * DD + s1b * 8;
  }

#define GLLB(T, SLOT)                                                            \
  {                                                                              \
    __builtin_amdgcn_global_load_lds(                                            \
        (const __attribute__((address_space(1))) void*)(srcB0 + (T) * 32),       \
        (__attribute__((address_space(3))) void*)(bufB + (SLOT) * 16384 + (wid * 2) * 1024), \
        16, 0, 0);                                                               \
    __builtin_amdgcn_global_load_lds(                                            \
        (const __attribute__((address_space(1))) void*)(srcB1 + (T) * 32),       \
        (__attribute__((address_space(3))) void*)(bufB + (SLOT) * 16384 + (wid * 2 + 1) * 1024), \
        16, 0, 0);                                                               \
  }

  int abase[2], as_[2];
#pragma unroll
  for (int mi = 0; mi < 2; ++mi) {
    int r = wr * 32 + mi * 16 + il;
    abase[mi] = r * 512;
    as_[mi] = r & 31;
  }
  int boffs[4];
#pragma unroll
  for (int ni = 0; ni < 4; ++ni) {
    int u = wc * 64 + ni * 16 + il;
    boffs[ni] = u * 64 + ((kg ^ ((u >> 1) & 3)) << 4);
  }

  f32x4 acc[2][4];
#pragma unroll
  for (int mi = 0; mi < 2; ++mi)
#pragma unroll
    for (int ni = 0; ni < 4; ++ni) {
      f32x4 z = {0.f, 0.f, 0.f, 0.f};
      acc[mi][ni] = z;
    }

  GLLB(0, 0);
  GLLB(1, 1);
  asm volatile("s_waitcnt vmcnt(2) lgkmcnt(0)" ::: "memory");
  __builtin_amdgcn_sched_barrier(0);
  __builtin_amdgcn_s_barrier();

#pragma unroll
  for (int t = 0; t < 8; ++t) {
    if (t < 6) GLLB(t + 2, (t + 2) % 3);
    const unsigned char* bC = bufB + (t % 3) * 16384;
    short8 af[2];
#pragma unroll
    for (int mi = 0; mi < 2; ++mi)
      af[mi] = *(const short8*)(smem + abase[mi] + (((4 * t + kg) ^ as_[mi]) << 4));
    __builtin_amdgcn_s_setprio(1);
#pragma unroll
    for (int ni = 0; ni < 4; ++ni) {
      short8 bf = *(const short8*)(bC + boffs[ni]);
      acc[0][ni] = __builtin_amdgcn_mfma_f32_16x16x32_bf16(af[0], bf, acc[0][ni], 0, 0, 0);
      acc[1][ni] = __builtin_amdgcn_mfma_f32_16x16x32_bf16(af[1], bf, acc[1][ni], 0, 0, 0);
    }
    __builtin_amdgcn_s_setprio(0);
    if (t < 6) {
      asm volatile("s_waitcnt vmcnt(2)" ::: "memory");
    } else if (t == 6) {
      asm volatile("s_waitcnt vmcnt(0)" ::: "memory");
    }
    if (t < 7) {
      __builtin_amdgcn_sched_barrier(0);
      __builtin_amdgcn_s_barrier();
    }
  }
#undef GLLB

  __syncthreads();

  // ---- epilogue overlay (A/B tiles dead) ----
  float (*red)[4] = (float (*)[4])smem;                 // [64][4]  (1 KB)
  float* pbuf     = (float*)(smem + 1024);              // [64]
  float4* pr      = (float4*)(smem + 2048);             // [512]    (8 KB)

  // per-lane posb/V fragments (L2-hot)
  float pv2[4], vvf[4];
#pragma unroll
  for (int ni = 0; ni < 4; ++ni) {
    int u = wc * 64 + ni * 16 + il;
    pv2[ni] = 2.f * posb[b * UU + u];
    vvf[ni] = V[u];
  }

  // tanh(acc + pv) * V accumulated per lane; tanh = 1 - 2/(e^{2x}+1)
  float part_r[2][4];
#pragma unroll
  for (int mi = 0; mi < 2; ++mi)
#pragma unroll
    for (int r = 0; r < 4; ++r) part_r[mi][r] = 0.f;

#pragma unroll
  for (int ni = 0; ni < 4; ++ni) {
    float p2 = pv2[ni], vv = vvf[ni];
#pragma unroll
    for (int mi = 0; mi < 2; ++mi)
#pragma unroll
      for (int r = 0; r < 4; ++r) {
        float x2 = fmaf(acc[mi][ni][r], 2.f, p2);
        float rc = __frcp_rn(__expf(x2) + 1.f);
        float tnh = fmaf(-2.f, rc, 1.f);
        part_r[mi][r] = fmaf(tnh, vv, part_r[mi][r]);
      }
  }
  // DPP row-reduce over il (16 lanes), VALU-rate
#pragma unroll
  for (int mi = 0; mi < 2; ++mi)
#pragma unroll
    for (int r = 0; r < 4; ++r) part_r[mi][r] = row16_sum(part_r[mi][r]);
  if (il == 0) {
#pragma unroll
    for (int mi = 0; mi < 2; ++mi)
#pragma unroll
      for (int r = 0; r < 4; ++r)
        red[wr * 32 + mi * 16 + kg * 4 + r][wc] = part_r[mi][r];
  }
  __syncthreads();

  // scores + unnormalized exp (fixed reference m=0; |score| <= ||V||_1+|bv| ~ 13)
  const float bvv = bvp[0];
  if (tid < 64) {
    float4 r0 = *(const float4*)red[tid];
    float sv = r0.x + r0.y + r0.z + r0.w + bvv;
    scores[(size_t)b * SS + s0 + tid] = sv;
    pbuf[tid] = __expf(sv);
  }
  __syncthreads();

  // partial context: fp32 re-read of the tile (L2/L3-hot), unnormalized
  {
    int rg = tid >> 6;
    int d4 = (tid & 63) << 2;
    float a0 = 0.f, a1 = 0.f, a2 = 0.f, a3 = 0.f;
#pragma unroll
    for (int i = 0; i < 8; ++i) {
      int s = i * 8 + rg;
      const float4 o = *(const float4*)(optb + (size_t)s * DD + d4);
      float w = pbuf[s];
      a0 = fmaf(w, o.x, a0); a1 = fmaf(w, o.y, a1);
      a2 = fmaf(w, o.z, a2); a3 = fmaf(w, o.w, a3);
    }
    pr[tid] = make_float4(a0, a1, a2, a3);
  }
  __syncthreads();
  if (tid < 64) {
    float4 o = pr[tid];
#pragma unroll
    for (int g = 1; g < 8; ++g) {
      float4 v = pr[g * 64 + tid];
      o.x += v.x; o.y += v.y; o.z += v.z; o.w += v.w;
    }
    *(float4*)&part[(((size_t)b * NCH + ch) * DD) + (tid << 2)] = o;
  }
}

// K3: per batch — gs from scores, emit context + weights
__global__ __launch_bounds__(256) void k_final(
    const float* __restrict__ scores, const float* __restrict__ part,
    float* __restrict__ ctx, float* __restrict__ wgt) {
  __shared__ float sred[4];
  int b = blockIdx.x, t = threadIdx.x;
  int lane = t & 63, wv = t >> 6;
  const float* sb = scores + (size_t)b * SS;
  float e[16];
  float psum = 0.f;
#pragma unroll
  for (int i = 0; i < 16; ++i) {
    e[i] = __expf(sb[i * 256 + t]);
    psum += e[i];
  }
#pragma unroll
  for (int off = 32; off >= 1; off >>= 1) psum += __shfl_xor(psum, off);
  if (lane == 0) sred[wv] = psum;
  __syncthreads();
  float gs = sred[0] + sred[1] + sred[2] + sred[3];
  float inv = 1.f / gs;
  float* wb = wgt + (size_t)b * SS;
#pragma unroll
  for (int i = 0; i < 16; ++i) wb[i * 256 + t] = e[i] * inv;
  float acc = 0.f;
#pragma unroll 4
  for (int i = 0; i < NCH; ++i)
    acc += part[((size_t)b * NCH + i) * DD + t];
  ctx[b * DD + t] = acc * inv;
}

extern "C" void kernel_launch(void* const* d_in, const int* in_sizes, int n_in,
                              void* d_out, int out_size, void* d_ws, size_t ws_size,
                              hipStream_t stream) {
  const float* position = (const float*)d_in[0];
  const float* options  = (const float*)d_in[1];
  const float* W1 = (const float*)d_in[2];
  const float* b1 = (const float*)d_in[3];
  const float* W2 = (const float*)d_in[4];
  const float* b2 = (const float*)d_in[5];
  const float* V  = (const float*)d_in[6];
  const float* bv = (const float*)d_in[7];

  float* out = (float*)d_out;
  float* ctx_out = out;              // [32,256]
  float* wgt_out = out + BB * DD;    // [32,4096]

  char* ws = (char*)d_ws;
  float* posb         = (float*)ws;                          // 32 KB
  unsigned short* w2t = (unsigned short*)(ws + 32 * 1024);   // 128 KB
  float* scores       = (float*)(ws + 160 * 1024);           // 512 KB
  float* part         = (float*)(ws + 672 * 1024);           // 2 MB

  k_posproj<<<BB, 256, 0, stream>>>(position, W1, b1, b2, posb);
  k_w2t<<<dim3(16, 16), 256, 0, stream>>>(W2, w2t);
  k_score_ctx<<<dim3(NCH, BB), 512, 0, stream>>>(options, w2t, posb, V, bv,
                                                 scores, part);
  k_final<<<BB, 256, 0, stream>>>(scores, part, ctx_out, wgt_out);
}